// Round 13
// baseline (726.459 us; speedup 1.0000x reference)
//
#include <hip/hip_runtime.h>
#include <cstdint>
#include <cstddef>

// MoNet (GMM graph conv) forward, MI355X — round 13 (= round-12 resubmit, unbenched).
// r11 measured 704 us: top = degree 66us (atomic floor); scatter/pull/gemm all <66.
// Pending delta: (1) float4 k-vectorized Xs reads in GEMM (LDS-bound: 8->5 LDS ops/16FMA),
// (2) pull gather unroll 8, (3) single w2_all_transform; sums zeroing folded into pull.

#define EPS 1e-5f
#define KAUG 196  // 192 m-columns + 3 gauss-sum columns + 1 zero pad

// ---------------- degree ----------------
__global__ void degree_kernel(const int* __restrict__ rowi, const int* __restrict__ coli,
                              int* __restrict__ dr, int* __restrict__ dc, int E) {
    int i = blockIdx.x * blockDim.x + threadIdx.x;
    int stride = gridDim.x * blockDim.x;
    for (; i < E; i += stride) {
        atomicAdd(&dr[rowi[i]], 1);
        atomicAdd(&dc[coli[i]], 1);
    }
}

// ---------------- hierarchical exclusive scan (3 phases) ----------------
__global__ __launch_bounds__(256) void scan_phase1(const int* __restrict__ cnt,
                                                   int* __restrict__ partial,
                                                   int* __restrict__ blockSum, int Nn) {
    __shared__ int sm[256];
    int tid = blockIdx.x * 256 + threadIdx.x;
    int v = (tid < Nn) ? cnt[tid] : 0;
    sm[threadIdx.x] = v;
    __syncthreads();
    for (int d = 1; d < 256; d <<= 1) {
        int t = (threadIdx.x >= d) ? sm[threadIdx.x - d] : 0;
        __syncthreads();
        sm[threadIdx.x] += t;
        __syncthreads();
    }
    if (tid < Nn) partial[tid] = sm[threadIdx.x] - v;  // exclusive within block
    if (threadIdx.x == 255) blockSum[blockIdx.x] = sm[255];
}

__global__ __launch_bounds__(1024) void scan_phase2(const int* __restrict__ blockSum,
                                                    int* __restrict__ blockOff, int B) {
    __shared__ int sm[1024];
    int v = (threadIdx.x < B) ? blockSum[threadIdx.x] : 0;
    sm[threadIdx.x] = v;
    __syncthreads();
    for (int d = 1; d < 1024; d <<= 1) {
        int t = (threadIdx.x >= d) ? sm[threadIdx.x - d] : 0;
        __syncthreads();
        sm[threadIdx.x] += t;
        __syncthreads();
    }
    if (threadIdx.x < B) blockOff[threadIdx.x] = sm[threadIdx.x] - v;  // exclusive
}

__global__ __launch_bounds__(256) void scan_phase3(const int* __restrict__ partial,
                                                   const int* __restrict__ blockOff,
                                                   int* __restrict__ start,
                                                   int* __restrict__ cursor, int Nn) {
    int tid = blockIdx.x * 256 + threadIdx.x;
    if (tid < Nn) {
        int s = partial[tid] + blockOff[blockIdx.x];
        start[tid] = s;
        cursor[tid] = s;
    }
}

// ---------------- fused scatter: degree->pseudo + counting-sort into 16B records ----------------
// perm[pos] = {rowbits, srcs=rsqrt(dr[r]+1), dsts=rsqrt(dc[d]+1), 0}
__global__ void csr_scatter(const int* __restrict__ rowi, const int* __restrict__ coli,
                            const int* __restrict__ dr, const int* __restrict__ dc,
                            int* __restrict__ cursor, float4* __restrict__ perm, int E) {
    int i = blockIdx.x * blockDim.x + threadIdx.x;
    int stride = gridDim.x * blockDim.x;
    for (; i < E; i += stride) {
        int r = rowi[i];
        int d = coli[i];
        int pos = atomicAdd(&cursor[d], 1);
        float a = rsqrtf((float)dr[r] + 1.0f);
        float b = rsqrtf((float)dc[d] + 1.0f);
        perm[pos] = make_float4(__int_as_float(r), a, b, 0.0f);
    }
}

// ---------------- W2 transform for all 4 layers in one dispatch ----------------
// W2 layout: layers 0..2 at i*KAUG*64 (C=64), last layer at 3*KAUG*64 (C=16).
// Rows 0..191: W2[(k*64+j)*C + c] = fcw[j*(3C) + k*C + c]; 192..194: bias; 195: 0.
__global__ void w2_all_transform(const float* __restrict__ fcw, const float* __restrict__ fcb,
                                 const float* __restrict__ fcwl, const float* __restrict__ fcbl,
                                 float* __restrict__ W2) {
    int i = blockIdx.x * blockDim.x + threadIdx.x;
    const int tot3 = 3 * KAUG * 64;
    if (i < tot3) {
        int layer = i / (KAUG * 64);
        int rem = i - layer * (KAUG * 64);
        int r = rem / 64, c = rem - r * 64;
        const float* fw = fcw + layer * 64 * 192;
        const float* fb = fcb + layer * 192;
        float v;
        if (r < 192) { int k = r >> 6, j = r & 63; v = fw[j * 192 + k * 64 + c]; }
        else if (r < 195) v = fb[(r - 192) * 64 + c];
        else v = 0.0f;
        W2[i] = v;
    } else {
        int rem = i - tot3;
        if (rem >= KAUG * 16) return;
        int r = rem / 16, c = rem - r * 16;
        float v;
        if (r < 192) { int k = r >> 6, j = r & 63; v = fcwl[j * 48 + k * 16 + c]; }
        else if (r < 195) v = fcbl[(r - 192) * 16 + c];
        else v = 0.0f;
        W2[i] = v;
    }
}

// ---------------- CSR pull with inline gauss: one wave per dst node, unroll 8 ----------------
// m[d, k*64+lane] = sum_e g_k(e) * h[row(e), lane]; m[d,192+k] = sum_e g_k
// Block 0 also zeroes sums[0..128) for the following bn_stats.
__global__ __launch_bounds__(256) void pull_kernel(const int* __restrict__ start,
                                                   const int* __restrict__ cnt,
                                                   const float4* __restrict__ perm,
                                                   const float* __restrict__ ppw,  // [2,2]
                                                   const float* __restrict__ ppb,  // [2]
                                                   const float* __restrict__ mu,   // [3,2]
                                                   const float* __restrict__ isg,  // [3,2]
                                                   const float* __restrict__ h,
                                                   float* __restrict__ m,
                                                   float* __restrict__ sums, int Nn) {
    if (blockIdx.x == 0 && threadIdx.x < 128) sums[threadIdx.x] = 0.0f;
    __shared__ float4 gl[4][64];  // per-wave slice; wave-coherent, no block barrier
    int wv = threadIdx.x >> 6;
    int lane = threadIdx.x & 63;
    int d = blockIdx.x * 4 + wv;
    if (d >= Nn) return;
    float w00 = ppw[0], w01 = ppw[1], w10 = ppw[2], w11 = ppw[3];
    float b0 = ppb[0], b1 = ppb[1];
    float m00 = mu[0], m01 = mu[1], m10 = mu[2], m11 = mu[3], m20 = mu[4], m21 = mu[5];
    float s00 = isg[0], s01 = isg[1], s10 = isg[2], s11 = isg[3], s20 = isg[4], s21 = isg[5];

    int s = start[d];
    int e = s + cnt[d];
    float a0 = 0.0f, a1 = 0.0f, a2 = 0.0f;
    float g0s = 0.0f, g1s = 0.0f, g2s = 0.0f;
    const float* hl = h + lane;

    for (int base = s; base < e; base += 64) {
        int idx = base + lane;
        float4 rec = make_float4(0.0f, 0.0f, 0.0f, 0.0f);
        if (idx < e) rec = perm[idx];
        // gauss for this edge (lane-parallel); invalid lanes compute on zeros (unread)
        float ps0 = tanhf(fmaf(rec.z, w10, fmaf(rec.y, w00, b0)));
        float ps1 = tanhf(fmaf(rec.z, w11, fmaf(rec.y, w01, b1)));
        float d0, d1;
        d0 = (ps0 - m00) * s00; d1 = (ps1 - m01) * s01;
        float g0 = expf(-0.5f * (d0 * d0 + d1 * d1));
        d0 = (ps0 - m10) * s10; d1 = (ps1 - m11) * s11;
        float g1 = expf(-0.5f * (d0 * d0 + d1 * d1));
        d0 = (ps0 - m20) * s20; d1 = (ps1 - m21) * s21;
        float g2 = expf(-0.5f * (d0 * d0 + d1 * d1));
        gl[wv][lane] = make_float4(g0, g1, g2, rec.x);  // rec.x = row bits

        int cb = e - base;
        if (cb > 64) cb = 64;
        int j = 0;
        for (; j + 7 < cb; j += 8) {
            float4 q0 = gl[wv][j],     q1 = gl[wv][j + 1], q2 = gl[wv][j + 2], q3 = gl[wv][j + 3];
            float4 q4 = gl[wv][j + 4], q5 = gl[wv][j + 5], q6 = gl[wv][j + 6], q7 = gl[wv][j + 7];
            float h0 = hl[(size_t)__float_as_int(q0.w) * 64];
            float h1 = hl[(size_t)__float_as_int(q1.w) * 64];
            float h2 = hl[(size_t)__float_as_int(q2.w) * 64];
            float h3 = hl[(size_t)__float_as_int(q3.w) * 64];
            float h4 = hl[(size_t)__float_as_int(q4.w) * 64];
            float h5 = hl[(size_t)__float_as_int(q5.w) * 64];
            float h6 = hl[(size_t)__float_as_int(q6.w) * 64];
            float h7 = hl[(size_t)__float_as_int(q7.w) * 64];
            a0 = fmaf(q0.x, h0, a0); a1 = fmaf(q0.y, h0, a1); a2 = fmaf(q0.z, h0, a2);
            a0 = fmaf(q1.x, h1, a0); a1 = fmaf(q1.y, h1, a1); a2 = fmaf(q1.z, h1, a2);
            a0 = fmaf(q2.x, h2, a0); a1 = fmaf(q2.y, h2, a1); a2 = fmaf(q2.z, h2, a2);
            a0 = fmaf(q3.x, h3, a0); a1 = fmaf(q3.y, h3, a1); a2 = fmaf(q3.z, h3, a2);
            a0 = fmaf(q4.x, h4, a0); a1 = fmaf(q4.y, h4, a1); a2 = fmaf(q4.z, h4, a2);
            a0 = fmaf(q5.x, h5, a0); a1 = fmaf(q5.y, h5, a1); a2 = fmaf(q5.z, h5, a2);
            a0 = fmaf(q6.x, h6, a0); a1 = fmaf(q6.y, h6, a1); a2 = fmaf(q6.z, h6, a2);
            a0 = fmaf(q7.x, h7, a0); a1 = fmaf(q7.y, h7, a1); a2 = fmaf(q7.z, h7, a2);
            g0s += q0.x + q1.x + q2.x + q3.x + q4.x + q5.x + q6.x + q7.x;
            g1s += q0.y + q1.y + q2.y + q3.y + q4.y + q5.y + q6.y + q7.y;
            g2s += q0.z + q1.z + q2.z + q3.z + q4.z + q5.z + q6.z + q7.z;
        }
        for (; j + 3 < cb; j += 4) {
            float4 q0 = gl[wv][j], q1 = gl[wv][j + 1], q2 = gl[wv][j + 2], q3 = gl[wv][j + 3];
            float h0 = hl[(size_t)__float_as_int(q0.w) * 64];
            float h1 = hl[(size_t)__float_as_int(q1.w) * 64];
            float h2 = hl[(size_t)__float_as_int(q2.w) * 64];
            float h3 = hl[(size_t)__float_as_int(q3.w) * 64];
            a0 = fmaf(q0.x, h0, a0); a1 = fmaf(q0.y, h0, a1); a2 = fmaf(q0.z, h0, a2);
            a0 = fmaf(q1.x, h1, a0); a1 = fmaf(q1.y, h1, a1); a2 = fmaf(q1.z, h1, a2);
            a0 = fmaf(q2.x, h2, a0); a1 = fmaf(q2.y, h2, a1); a2 = fmaf(q2.z, h2, a2);
            a0 = fmaf(q3.x, h3, a0); a1 = fmaf(q3.y, h3, a1); a2 = fmaf(q3.z, h3, a2);
            g0s += q0.x + q1.x + q2.x + q3.x;
            g1s += q0.y + q1.y + q2.y + q3.y;
            g2s += q0.z + q1.z + q2.z + q3.z;
        }
        for (; j < cb; ++j) {
            float4 q0 = gl[wv][j];
            float h0 = hl[(size_t)__float_as_int(q0.w) * 64];
            a0 = fmaf(q0.x, h0, a0); a1 = fmaf(q0.y, h0, a1); a2 = fmaf(q0.z, h0, a2);
            g0s += q0.x; g1s += q0.y; g2s += q0.z;
        }
    }
    float* mr = m + (size_t)d * KAUG;
    mr[lane] = a0;
    mr[64 + lane] = a1;
    mr[128 + lane] = a2;
    if (lane < 3) mr[192 + lane] = (lane == 0) ? g0s : ((lane == 1) ? g1s : g2s);
    if (lane == 3) mr[195] = 0.0f;
}

// ---------------- GEMM: Y[M,NC] = X[M,KDIM] @ W[KDIM,NC] (+ b if Bv) ----------------
// Xs padded to KDIM+8 (16B-aligned rows, bank-spread) for float4 k-reads.
template <int KDIM, int NC, int ROWS>
__global__ __launch_bounds__(256) void gemm_bias(const float* __restrict__ X,
                                                 const float* __restrict__ W,
                                                 const float* __restrict__ Bv,
                                                 float* __restrict__ Y, int M) {
    constexpr int TPR = 256 / ROWS;  // threads per row
    constexpr int CPT = NC / TPR;    // cols per thread (contiguous)
    constexpr int XP = KDIM + 8;     // 196->204, 128->136; both %4==0, rows 16B-aligned
    __shared__ __align__(16) float Ws[KDIM * NC];
    __shared__ float Bs[NC];
    __shared__ __align__(16) float Xs[ROWS][XP];

    for (int i = threadIdx.x; i < KDIM * NC; i += 256) Ws[i] = W[i];
    if (Bv && threadIdx.x < NC) Bs[threadIdx.x] = Bv[threadIdx.x];
    int row0 = blockIdx.x * ROWS;
    for (int i = threadIdx.x; i < ROWS * KDIM; i += 256) {
        int r = i / KDIM, k = i - r * KDIM;
        int gr = row0 + r;
        Xs[r][k] = (gr < M) ? X[(size_t)gr * KDIM + k] : 0.0f;
    }
    __syncthreads();

    int r = threadIdx.x / TPR;
    int lc = threadIdx.x % TPR;
    int gr = row0 + r;

    float acc[CPT];
#pragma unroll
    for (int j = 0; j < CPT; ++j) acc[j] = Bv ? Bs[lc * CPT + j] : 0.0f;
    for (int k4 = 0; k4 < KDIM; k4 += 4) {  // KDIM%4==0 for 196 and 128
        float4 xv = *reinterpret_cast<const float4*>(&Xs[r][k4]);
        const float* w0 = &Ws[k4 * NC + lc * CPT];
#pragma unroll
        for (int j = 0; j < CPT; ++j) acc[j] = fmaf(xv.x, w0[j], acc[j]);
#pragma unroll
        for (int j = 0; j < CPT; ++j) acc[j] = fmaf(xv.y, w0[NC + j], acc[j]);
#pragma unroll
        for (int j = 0; j < CPT; ++j) acc[j] = fmaf(xv.z, w0[2 * NC + j], acc[j]);
#pragma unroll
        for (int j = 0; j < CPT; ++j) acc[j] = fmaf(xv.w, w0[3 * NC + j], acc[j]);
    }
    if (gr < M) {
        float* yr = Y + (size_t)gr * NC + lc * CPT;
#pragma unroll
        for (int j = 0; j < CPT; ++j) yr[j] = acc[j];
    }
}

// ---------------- BN stats: per-channel sum & sumsq ----------------
template <int C>
__global__ __launch_bounds__(256) void bn_stats(const float* __restrict__ x, int Nn,
                                                float* __restrict__ sums) {
    constexpr int G = 256 / C;
    int c = threadIdx.x % C;
    int g = threadIdx.x / C;
    float s = 0.0f, ss = 0.0f;
    int totalG = gridDim.x * G;
    for (int r = blockIdx.x * G + g; r < Nn; r += totalG) {
        float v = x[(size_t)r * C + c];
        s += v;
        ss += v * v;
    }
    __shared__ float ls[256], lss[256];
    ls[threadIdx.x] = s;
    lss[threadIdx.x] = ss;
    __syncthreads();
    if (threadIdx.x < C) {
        float ts = 0.0f, tss = 0.0f;
#pragma unroll
        for (int gg = 0; gg < G; ++gg) {
            ts += ls[gg * C + threadIdx.x];
            tss += lss[gg * C + threadIdx.x];
        }
        atomicAdd(&sums[threadIdx.x], ts);
        atomicAdd(&sums[C + threadIdx.x], tss);
    }
}

// ---------------- BN apply + relu (+ residual) ----------------
template <int C, bool RES>
__global__ __launch_bounds__(256) void bn_apply(const float* __restrict__ agg,
                                                const float* __restrict__ sums,
                                                const float* __restrict__ gam,
                                                const float* __restrict__ bet,
                                                const float* __restrict__ hin,
                                                float* __restrict__ hout, int Nn) {
    size_t i = (size_t)blockIdx.x * blockDim.x + threadIdx.x;
    size_t tot = (size_t)Nn * C;
    size_t stride = (size_t)gridDim.x * blockDim.x;
    float invN = 1.0f / (float)Nn;
    for (; i < tot; i += stride) {
        int c = (int)(i & (C - 1));
        float mean = sums[c] * invN;
        float var = sums[C + c] * invN - mean * mean;
        float scale = gam[c] * rsqrtf(var + EPS);
        float v = (agg[i] - mean) * scale + bet[c];
        v = fmaxf(v, 0.0f);
        if (RES) v += hin[i];
        hout[i] = v;
    }
}

extern "C" void kernel_launch(void* const* d_in, const int* in_sizes, int n_in,
                              void* d_out, int out_size, void* d_ws, size_t ws_size,
                              hipStream_t stream) {
    const float* feature = (const float*)d_in[0];
    const float* emb_w = (const float*)d_in[1];
    const float* emb_b = (const float*)d_in[2];
    const float* fc_w = (const float*)d_in[3];    // [3,64,192]
    const float* fc_b = (const float*)d_in[4];    // [3,192]
    const float* mu = (const float*)d_in[5];      // [3,3,2]
    const float* isg = (const float*)d_in[6];     // [3,3,2]
    const float* pp_w = (const float*)d_in[7];    // [3,2,2]
    const float* pp_b = (const float*)d_in[8];    // [3,2]
    const float* bn_g = (const float*)d_in[9];    // [3,64]
    const float* bn_b = (const float*)d_in[10];   // [3,64]
    const float* fc_w_l = (const float*)d_in[11]; // [64,48]
    const float* fc_b_l = (const float*)d_in[12]; // [48]
    const float* mu_l = (const float*)d_in[13];   // [3,2]
    const float* isg_l = (const float*)d_in[14];  // [3,2]
    const float* pp_w_l = (const float*)d_in[15]; // [2,2]
    const float* pp_b_l = (const float*)d_in[16]; // [2]
    const float* bn_g_l = (const float*)d_in[17]; // [16]
    const float* bn_b_l = (const float*)d_in[18]; // [16]
    const int* edge = (const int*)d_in[19];       // [2,E] int32

    const int N = in_sizes[0] / 128;
    const int E = in_sizes[19] / 2;
    const int* rowi = edge;
    const int* coli = edge + E;

    char* ws = (char*)d_ws;
    size_t off = 0;
    auto alloc = [&](size_t sz) -> void* {
        void* p = ws + off;
        off += (sz + 255) & ~(size_t)255;
        return p;
    };
    int* dr = (int*)alloc((size_t)N * 4);
    int* dc = (int*)alloc((size_t)N * 4);           // in-degree by col (CSR counts)
    int* startv = (int*)alloc((size_t)N * 4);
    int* cursor = (int*)alloc((size_t)N * 4);
    int* partial = (int*)alloc((size_t)N * 4);
    int* blockSum = (int*)alloc(1024 * 4);
    int* blockOff = (int*)alloc(1024 * 4);
    float4* perm = (float4*)alloc((size_t)E * 16); // {rowbits, srcs, dsts, 0} per edge
    float* h = (float*)alloc((size_t)N * 64 * 4);
    float* m = (float*)alloc((size_t)N * KAUG * 4);
    float* agg = (float*)alloc((size_t)N * 64 * 4);
    float* W2 = (float*)alloc((size_t)(3 * KAUG * 64 + KAUG * 16) * 4);
    float* sums = (float*)alloc(2 * 64 * 4);
    (void)ws_size; // ~75 MB

    hipMemsetAsync(dr, 0, (size_t)N * 4, stream);
    hipMemsetAsync(dc, 0, (size_t)N * 4, stream);
    degree_kernel<<<2048, 256, 0, stream>>>(rowi, coli, dr, dc, E);

    const int scanB = (N + 255) / 256;  // 196 for N=50000 (must be <= 1024)
    scan_phase1<<<scanB, 256, 0, stream>>>(dc, partial, blockSum, N);
    scan_phase2<<<1, 1024, 0, stream>>>(blockSum, blockOff, scanB);
    scan_phase3<<<scanB, 256, 0, stream>>>(partial, blockOff, startv, cursor, N);

    csr_scatter<<<2048, 256, 0, stream>>>(rowi, coli, dr, dc, cursor, perm, E);

    // All 4 layers' W2 in one dispatch (3*196*64 + 196*16 = 40768 elements)
    w2_all_transform<<<(3 * KAUG * 64 + KAUG * 16 + 255) / 256, 256, 0, stream>>>(
        fc_w, fc_b, fc_w_l, fc_b_l, W2);

    // h = feature @ emb_w + emb_b   [N,128]x[128,64]
    gemm_bias<128, 64, 32><<<(N + 31) / 32, 256, 0, stream>>>(feature, emb_w, emb_b, h, N);

    const int pullBlocks = (N + 3) / 4;
    for (int i = 0; i < 3; ++i) {
        pull_kernel<<<pullBlocks, 256, 0, stream>>>(startv, dc, perm,
                                                    pp_w + i * 4, pp_b + i * 2,
                                                    mu + i * 6, isg + i * 6, h, m, sums, N);
        gemm_bias<KAUG, 64, 16><<<(N + 15) / 16, 256, 0, stream>>>(
            m, W2 + (size_t)i * KAUG * 64, nullptr, agg, N);
        bn_stats<64><<<256, 256, 0, stream>>>(agg, N, sums);
        bn_apply<64, true><<<2048, 256, 0, stream>>>(agg, sums, bn_g + i * 64, bn_b + i * 64,
                                                     h, h, N);
    }

    // last layer: 16 classes, no residual, write d_out (f32)
    pull_kernel<<<pullBlocks, 256, 0, stream>>>(startv, dc, perm,
                                                pp_w_l, pp_b_l, mu_l, isg_l, h, m, sums, N);
    gemm_bias<KAUG, 16, 32><<<(N + 31) / 32, 256, 0, stream>>>(
        m, W2 + (size_t)3 * KAUG * 64, nullptr, agg, N);
    bn_stats<16><<<256, 256, 0, stream>>>(agg, N, sums);
    bn_apply<16, false><<<2048, 256, 0, stream>>>(agg, sums, bn_g_l, bn_b_l, nullptr,
                                                  (float*)d_out, N);
}